// Round 1
// baseline (132.353 us; speedup 1.0000x reference)
//
#include <hip/hip_runtime.h>

// Problem constants
#define Vn 128
#define Sn 32
#define En 16
#define M0 128
#define Ln 128
#define Bn 16
#define Nn 127
#define BTn 2048
#define RS 20   // padded LDS row stride (dwords) for gather tables

__global__ __launch_bounds__(256, 4) void memnet_main(
    const float* __restrict__ node_fts, const float* __restrict__ edge_fts,
    const float* __restrict__ graph_fts, const float* __restrict__ adjm,
    const float* __restrict__ enc, const float* __restrict__ qb,
    const float* __restrict__ sb, const float* __restrict__ ob,
    const float* __restrict__ mc, const float* __restrict__ wout,
    const float* __restrict__ wfin, float* __restrict__ ret)
{
    __shared__ __align__(16) float sbL[M0 * RS];
    __shared__ __align__(16) float obL[M0 * RS];
    __shared__ __align__(16) float encL[Sn * En];
    __shared__ unsigned int idxw[M0 * 8];       // 32 uint8 idx per slot, packed
    __shared__ float cjT[En * 129];             // Cj transposed, stride 129
    __shared__ float scoresL[M0];
    __shared__ float probsL[M0];
    __shared__ float opart[128];
    __shared__ float uL[En];
    __shared__ float uoL[En];
    __shared__ float xL[Ln];
    __shared__ float red[8];

    const int t = threadIdx.x;
    const int bt = blockIdx.x;
    const int b = bt >> 7;     // batch
    const int i = bt & 127;    // node row (127 == graph-feature row)

    // ---- stage sb/ob tables (127 rows + zero nil row), padded stride ----
    for (int c = t; c < 512; c += 256) {
        int r = c >> 2, q = c & 3;
        float4 v = make_float4(0.f, 0.f, 0.f, 0.f);
        float4 w = make_float4(0.f, 0.f, 0.f, 0.f);
        if (r < 127) {
            v = *(const float4*)&sb[r * 16 + q * 4];
            w = *(const float4*)&ob[r * 16 + q * 4];
        }
        *(float4*)&sbL[r * RS + q * 4] = v;
        *(float4*)&obL[r * RS + q * 4] = w;
    }
    // ---- stage enc ----
    if (t < 128) {
        *(float4*)&encL[t * 4] = *(const float4*)&enc[t * 4];
    }
    // ---- build index tile: idx = int(edge * adj), 0 for pads ----
    for (int c = t; c < 1024; c += 256) {
        int m = c >> 3, q = c & 7;
        unsigned int packed = 0u;
        if (i < 127 && m < 127) {
            float a = adjm[(b * 127 + i) * 127 + m];
            if (a != 0.f) {
                const float4 v = *(const float4*)&edge_fts[(size_t)(((b * 127 + i) * 127 + m)) * 32 + q * 4];
                packed = (unsigned)(int)v.x | ((unsigned)(int)v.y << 8)
                       | ((unsigned)(int)v.z << 16) | ((unsigned)(int)v.w << 24);
            }
        }
        idxw[m * 8 + q] = packed;
    }
    // ---- u[e] = sum_s qb[qidx[s]][e] * enc[s][e] ----
    if (t < 16) {
        float ue = 0.f;
        for (int s = 0; s < 32; s++) {
            float qv = (i < 127) ? node_fts[(b * 127 + i) * 32 + s] : graph_fts[b * 32 + s];
            int qi = (int)qv;
            if (qi < 0) qi = 0;
            float w = (qi < 127) ? qb[qi * 16 + t] : 0.f;
            ue = fmaf(w, enc[s * 16 + t], ue);
        }
        uL[t] = ue;
    }
    __syncthreads();

    // ---- gather phase: thread = (slot-duo md, e-group eg) ----
    const int eg4 = (t & 3) * 4;
    const int md = t >> 2;          // 0..63
    const int m0 = md;
    const int m1 = md + 64;

    float4 aM0 = make_float4(0.f, 0.f, 0.f, 0.f);
    float4 aM1 = make_float4(0.f, 0.f, 0.f, 0.f);
    float4 aC0 = make_float4(0.f, 0.f, 0.f, 0.f);
    float4 aC1 = make_float4(0.f, 0.f, 0.f, 0.f);

    for (int sq = 0; sq < 8; sq++) {
        unsigned w0 = idxw[m0 * 8 + sq];
        unsigned w1 = idxw[m1 * 8 + sq];
#pragma unroll
        for (int j = 0; j < 4; j++) {
            int s = sq * 4 + j;
            int i0 = (w0 >> (8 * j)) & 0xFF;
            int i1 = (w1 >> (8 * j)) & 0xFF;
            float4 eb = *(const float4*)&encL[s * 16 + eg4];
            float4 a0 = *(const float4*)&sbL[i0 * RS + eg4];
            float4 c0 = *(const float4*)&obL[i0 * RS + eg4];
            float4 a1 = *(const float4*)&sbL[i1 * RS + eg4];
            float4 c1 = *(const float4*)&obL[i1 * RS + eg4];
            aM0.x = fmaf(a0.x, eb.x, aM0.x); aM0.y = fmaf(a0.y, eb.y, aM0.y);
            aM0.z = fmaf(a0.z, eb.z, aM0.z); aM0.w = fmaf(a0.w, eb.w, aM0.w);
            aC0.x = fmaf(c0.x, eb.x, aC0.x); aC0.y = fmaf(c0.y, eb.y, aC0.y);
            aC0.z = fmaf(c0.z, eb.z, aC0.z); aC0.w = fmaf(c0.w, eb.w, aC0.w);
            aM1.x = fmaf(a1.x, eb.x, aM1.x); aM1.y = fmaf(a1.y, eb.y, aM1.y);
            aM1.z = fmaf(a1.z, eb.z, aM1.z); aM1.w = fmaf(a1.w, eb.w, aM1.w);
            aC1.x = fmaf(c1.x, eb.x, aC1.x); aC1.y = fmaf(c1.y, eb.y, aC1.y);
            aC1.z = fmaf(c1.z, eb.z, aC1.z); aC1.w = fmaf(c1.w, eb.w, aC1.w);
        }
    }

    // ---- scores: dot(mem + memory_contents, u); Cj -> transposed LDS ----
    {
        float4 u4 = *(const float4*)&uL[eg4];
        float4 mc0 = *(const float4*)&mc[m0 * 16 + eg4];
        float4 mc1 = *(const float4*)&mc[m1 * 16 + eg4];
        float p0 = (aM0.x + mc0.x) * u4.x + (aM0.y + mc0.y) * u4.y
                 + (aM0.z + mc0.z) * u4.z + (aM0.w + mc0.w) * u4.w;
        float p1 = (aM1.x + mc1.x) * u4.x + (aM1.y + mc1.y) * u4.y
                 + (aM1.z + mc1.z) * u4.z + (aM1.w + mc1.w) * u4.w;
        p0 += __shfl_xor(p0, 1); p0 += __shfl_xor(p0, 2);
        p1 += __shfl_xor(p1, 1); p1 += __shfl_xor(p1, 2);
        if ((t & 3) == 0) { scoresL[m0] = p0; scoresL[m1] = p1; }
        cjT[(eg4 + 0) * 129 + m0] = aC0.x; cjT[(eg4 + 1) * 129 + m0] = aC0.y;
        cjT[(eg4 + 2) * 129 + m0] = aC0.z; cjT[(eg4 + 3) * 129 + m0] = aC0.w;
        cjT[(eg4 + 0) * 129 + m1] = aC1.x; cjT[(eg4 + 1) * 129 + m1] = aC1.y;
        cjT[(eg4 + 2) * 129 + m1] = aC1.z; cjT[(eg4 + 3) * 129 + m1] = aC1.w;
    }
    __syncthreads();

    // ---- softmax over 128 slots ----
    {
        float v = (t < 128) ? scoresL[t] : -1e30f;
#pragma unroll
        for (int off = 32; off > 0; off >>= 1) v = fmaxf(v, __shfl_xor(v, off));
        if ((t & 63) == 0) red[t >> 6] = v;
        __syncthreads();
        float mx = fmaxf(fmaxf(red[0], red[1]), fmaxf(red[2], red[3]));
        float ex = (t < 128) ? __expf(scoresL[t] - mx) : 0.f;
        float sv = ex;
#pragma unroll
        for (int off = 32; off > 0; off >>= 1) sv += __shfl_xor(sv, off);
        __syncthreads();
        if ((t & 63) == 0) red[t >> 6] = sv;
        __syncthreads();
        float sum = red[0] + red[1] + red[2] + red[3];
        if (t < 128) probsL[t] = ex / sum;
    }
    __syncthreads();

    // ---- o[e] = sum_m probs[m] * Cj[m][e] ----
    if (t < 128) {
        int e = t & 15, ch = t >> 4;
        float acc = 0.f;
#pragma unroll
        for (int k = 0; k < 16; k++) {
            int m = ch * 16 + k;
            acc = fmaf(probsL[m], cjT[e * 129 + m], acc);
        }
        opart[t] = acc;
    }
    __syncthreads();
    if (t < 16) {
        float o = 0.f;
#pragma unroll
        for (int ch = 0; ch < 8; ch++) o += opart[ch * 16 + t];
        uoL[t] = uL[t] + o;
    }
    __syncthreads();

    // ---- x = relu((u+o) @ W_out) ----
    if (t < 128) {
        float acc = 0.f;
#pragma unroll
        for (int e = 0; e < 16; e++) acc = fmaf(uoL[e], wout[e * 128 + t], acc);
        xL[t] = fmaxf(acc, 0.f);
    }
    __syncthreads();
    // ---- ret = x @ W_fin ----
    if (t < 128) {
        float acc = 0.f;
        for (int l = 0; l < 128; l++) acc = fmaf(xL[l], wfin[l * 128 + t], acc);
        ret[bt * 128 + t] = acc;
    }
}

// out[b,i,v] = ret[b,i,v] + ret[b,127,v]
__global__ void memnet_out(const float* __restrict__ ret, float* __restrict__ out)
{
    int idx = blockIdx.x * 256 + threadIdx.x;
    if (idx >= Bn * Nn * Vn) return;
    int v = idx & 127;
    int r = idx >> 7;          // b*127 + i
    int b = r / 127;
    int i = r - b * 127;
    out[idx] = ret[(b * 128 + i) * 128 + v] + ret[(b * 128 + 127) * 128 + v];
}

extern "C" void kernel_launch(void* const* d_in, const int* in_sizes, int n_in,
                              void* d_out, int out_size, void* d_ws, size_t ws_size,
                              hipStream_t stream)
{
    const float* node  = (const float*)d_in[0];
    const float* edge  = (const float*)d_in[1];
    const float* graph = (const float*)d_in[2];
    const float* adjm  = (const float*)d_in[3];
    // d_in[4] = hidden (unused)
    const float* enc   = (const float*)d_in[5];
    const float* qb    = (const float*)d_in[6];
    const float* sb    = (const float*)d_in[7];
    const float* ob    = (const float*)d_in[8];
    const float* mc    = (const float*)d_in[9];
    // d_in[10] = W_int (unused, num_hops == 1)
    const float* wout  = (const float*)d_in[11];
    const float* wfin  = (const float*)d_in[12];

    float* ws = (float*)d_ws;   // BTn * 128 floats = 1 MB scratch

    memnet_main<<<BTn, 256, 0, stream>>>(node, edge, graph, adjm, enc, qb,
                                         sb, ob, mc, wout, wfin, ws);
    const int total = Bn * Nn * Vn;
    memnet_out<<<(total + 255) / 256, 256, 0, stream>>>(ws, (float*)d_out);
}